// Round 1
// baseline (645.716 us; speedup 1.0000x reference)
//
#include <hip/hip_runtime.h>

#define NN 100000
#define NE 1600000
#define NEG_SLOPE 0.01f

// ---------------------------------------------------------------------------
// Layer-1 aggregation: agg[dst, f] += w * feats[src, f], F=64.
// One wave (64 lanes) per edge; lane = feature. Edge-scalar loads are
// wave-uniform (one cache line); gather/scatter are 256B contiguous per wave.
__global__ __launch_bounds__(256) void k_agg64(
    const float* __restrict__ feats, const int* __restrict__ src,
    const int* __restrict__ dst, const float* __restrict__ ew,
    float* __restrict__ agg)
{
    int gid = blockIdx.x * 256 + threadIdx.x;
    int e = gid >> 6;
    int f = gid & 63;
    int s = src[e];
    int d = dst[e];
    float w = ew[e];
    atomicAdd(&agg[d * 64 + f], w * feats[s * 64 + f]);
}

// ---------------------------------------------------------------------------
// Fused per-node MLP: h = lrelu(agg_row @ W1 + b1); hw = h @ W2.
// hw (32 floats) is written IN PLACE into the first 32 floats of the agg row
// (row stride stays 64) so total workspace = N*64 floats.
// One wave per node; W1 (16KB), W2 (8KB), b1 in LDS.
__global__ __launch_bounds__(256) void k_mlp(
    float* __restrict__ agg, const float* __restrict__ W1,
    const float* __restrict__ b1, const float* __restrict__ W2)
{
    __shared__ float sW1[64][64];
    __shared__ float sW2[64][32];
    __shared__ float sb1[64];
    int tid = threadIdx.x;
    for (int i = tid; i < 64 * 64; i += 256) sW1[i >> 6][i & 63] = W1[i];
    for (int i = tid; i < 64 * 32; i += 256) sW2[i >> 5][i & 31] = W2[i];
    if (tid < 64) sb1[tid] = b1[tid];
    __syncthreads();

    int lane = tid & 63;
    int wave = tid >> 6;
    int wid = blockIdx.x * 4 + wave;
    int nwaves = gridDim.x * 4;

    for (int r = wid; r < NN; r += nwaves) {
        float a = agg[r * 64 + lane];          // coalesced 256B row read
        float h = sb1[lane];
        #pragma unroll
        for (int k = 0; k < 64; ++k)
            h = fmaf(__shfl(a, k, 64), sW1[k][lane], h);
        h = (h >= 0.f) ? h : NEG_SLOPE * h;

        // hw[c] = sum_k h[k] * W2[k][c]; split k-range across the two halves
        int half = lane >> 5;
        int c = lane & 31;
        float p = 0.f;
        #pragma unroll
        for (int kk = 0; kk < 32; ++kk) {
            int k = (half << 5) + kk;
            p = fmaf(__shfl(h, k, 64), sW2[k][c], p);
        }
        p += __shfl_xor(p, 32, 64);            // combine the two k-halves
        if (lane < 32) agg[r * 64 + lane] = p; // in-place, stride-64 rows
    }
}

// ---------------------------------------------------------------------------
// out[n, c] = b2[c]  (aggregation for layer 2 atomically accumulates on top)
__global__ __launch_bounds__(256) void k_init_out(
    float* __restrict__ out, const float* __restrict__ b2)
{
    int gid = blockIdx.x * 256 + threadIdx.x;
    out[gid] = b2[gid & 31];
}

// ---------------------------------------------------------------------------
// Layer-2 aggregation on the PRE-multiplied features (A@(h@W2) == (A@h)@W2):
// out[dst, f] += w * hw[src, f], F=32 (hw stored with row stride 64).
__global__ __launch_bounds__(256) void k_agg32(
    const float* __restrict__ hw, const int* __restrict__ src,
    const int* __restrict__ dst, const float* __restrict__ ew,
    float* __restrict__ out)
{
    int gid = blockIdx.x * 256 + threadIdx.x;
    int e = gid >> 5;
    int f = gid & 31;
    int s = src[e];
    int d = dst[e];
    float w = ew[e];
    atomicAdd(&out[d * 32 + f], w * hw[s * 64 + f]);
}

// ---------------------------------------------------------------------------
extern "C" void kernel_launch(void* const* d_in, const int* in_sizes, int n_in,
                              void* d_out, int out_size, void* d_ws, size_t ws_size,
                              hipStream_t stream)
{
    const float* feats = (const float*)d_in[0];
    const int*   esrc  = (const int*)d_in[1];
    const int*   edst  = (const int*)d_in[2];
    const float* ew    = (const float*)d_in[3];
    const float* W1    = (const float*)d_in[4];
    const float* b1    = (const float*)d_in[5];
    const float* W2    = (const float*)d_in[6];
    const float* b2    = (const float*)d_in[7];
    float* out = (float*)d_out;
    float* agg = (float*)d_ws;   // N*64 floats = 25.6 MB

    hipMemsetAsync(agg, 0, (size_t)NN * 64 * sizeof(float), stream);

    k_agg64<<<(NE * 64) / 256, 256, 0, stream>>>(feats, esrc, edst, ew, agg);
    k_mlp<<<2048, 256, 0, stream>>>(agg, W1, b1, W2);
    k_init_out<<<(NN * 32) / 256, 256, 0, stream>>>(out, b2);
    k_agg32<<<(NE * 32) / 256, 256, 0, stream>>>(agg, esrc, edst, ew, out);
}